// Round 4
// baseline (74.413 us; speedup 1.0000x reference)
//
#include <hip/hip_runtime.h>
#include <stdint.h>

// loss = mean_b sum_t [ valid * ( lse(x) - (S/C)*sum_c x_c - (1-S)*x_label ) ]
// Memory-bound: 125.8 MB pred (f32) + 41.9 MB labels (i32) -> one f32 out.
// Single fused kernel: double-buffered LDS chunks + global_load_lds prefetch,
// then last-block-done final reduce (kills the stage2 launch + graph gap).

constexpr int   FILLUP  = -100;
constexpr float BASEP   = 0.2f / 3.0f;   // SMOOTHING / C
constexpr float CONF    = 0.8f;          // 1 - SMOOTHING
constexpr int   NB      = 2097152;       // B
constexpr int   THREADS = 256;
constexpr int   CROWS   = 256;                    // rows per chunk
constexpr int   NCHUNK  = NB / CROWS;             // 8192
constexpr int   CPB     = 8;                      // chunks per block
constexpr int   NBLOCKS = NCHUNK / CPB;           // 1024 = 4/CU x 256 CU
constexpr int   PRED_CB = CROWS * 15 * 4;         // 15360 B per chunk
constexpr int   LAB_CB  = CROWS * 5 * 4;          // 5120 B per chunk
constexpr int   PRED_SLOTS = PRED_CB / 16;        // 960 x 16B
constexpr int   LAB_SLOTS  = LAB_CB / 16;         // 320 x 16B

__device__ __forceinline__ void gll16(const void* g, void* l) {
    // async global->LDS, width 16B; LDS dest = wave-uniform base + lane*16
    __builtin_amdgcn_global_load_lds(
        (const __attribute__((address_space(1))) void*)g,
        (__attribute__((address_space(3))) void*)l, 16, 0, 0);
}

__device__ __forceinline__ void stage_chunk(const char* __restrict__ predB,
                                            const char* __restrict__ labB,
                                            int chunk, char* predL, char* labL,
                                            int t) {
    const char* ps = predB + (size_t)chunk * PRED_CB;
    const char* ls = labB  + (size_t)chunk * LAB_CB;
#pragma unroll
    for (int i = 0; i < 4; ++i) {                 // 960 slots: 3.75 iters (wave-aligned)
        const int idx = i * THREADS + t;
        if (idx < PRED_SLOTS) gll16(ps + (size_t)idx * 16, predL + idx * 16);
    }
#pragma unroll
    for (int i = 0; i < 2; ++i) {                 // 320 slots: 1.25 iters
        const int idx = i * THREADS + t;
        if (idx < LAB_SLOTS) gll16(ls + (size_t)idx * 16, labL + idx * 16);
    }
}

__global__ __launch_bounds__(THREADS)
void ce_lsr_fused(const char* __restrict__ predB,
                  const char* __restrict__ labB,
                  float* __restrict__ partial,
                  unsigned* __restrict__ counter,
                  float* __restrict__ out) {
    // 2 x (15360 + 5120) = 40960 B exactly -> 4 blocks/CU (16 waves)
    __shared__ __align__(16) char predS[2][PRED_CB];
    __shared__ __align__(16) char labS[2][LAB_CB];
    __shared__ bool isLast;

    const int t = threadIdx.x;
    const int cbase = blockIdx.x * CPB;

    stage_chunk(predB, labB, cbase, predS[0], labS[0], t);   // cold start (once)
    __syncthreads();                                         // vmcnt(0) drain

    float acc = 0.0f;
    for (int k = 0; k < CPB; ++k) {
        const int cur = k & 1;
        if (k + 1 < CPB)                                     // prefetch BEFORE compute
            stage_chunk(predB, labB, cbase + k + 1, predS[cur ^ 1], labS[cur ^ 1], t);

        // compute chunk k: 1 row/thread; LDS row stride 15 dwords
        // (gcd(15,32)=1 -> 2-way bank aliasing across 64 lanes = free, m136)
        const float* __restrict__ xr = (const float*)(predS[cur]) + t * 15;
        const int*   __restrict__ lr = (const int*)(labS[cur]) + t * 5;
#pragma unroll
        for (int tt = 0; tt < 5; ++tt) {
            const int   l  = lr[tt];
            const float x0 = xr[tt];
            const float x1 = xr[5 + tt];
            const float x2 = xr[10 + tt];
            const float m   = fmaxf(fmaxf(x0, x1), x2);
            const float s   = __expf(x0 - m) + __expf(x1 - m) + __expf(x2 - m);
            const float lse = m + __logf(s);
            const float xl  = (l == 1) ? x1 : ((l == 2) ? x2 : x0);
            const float c   = lse - BASEP * (x0 + x1 + x2) - CONF * xl;
            acc += (l != FILLUP) ? c : 0.0f;
        }
        __syncthreads();   // drains prefetch (k+1 ready) + protects buf reuse
    }

    // block reduce: wave shuffle, then cross-wave via reused staging LDS
#pragma unroll
    for (int off = 32; off > 0; off >>= 1)
        acc += __shfl_down(acc, off, 64);

    float* wsum = (float*)predS;          // safe: loop-end barrier passed
    if ((t & 63) == 0) wsum[t >> 6] = acc;
    __syncthreads();

    if (t == 0) {
        const float s = wsum[0] + wsum[1] + wsum[2] + wsum[3];
        // release: partial visible at device scope before counter bump
        __hip_atomic_store(&partial[blockIdx.x], s,
                           __ATOMIC_RELEASE, __HIP_MEMORY_SCOPE_AGENT);
        const unsigned prev = __hip_atomic_fetch_add(counter, 1u,
                           __ATOMIC_ACQ_REL, __HIP_MEMORY_SCOPE_AGENT);
        isLast = (prev == NBLOCKS - 1);
    }
    __syncthreads();

    if (isLast) {
        // exactly one block runs this; fixed reduction tree -> deterministic
        float a = 0.0f;
#pragma unroll
        for (int i = 0; i < NBLOCKS / THREADS; ++i)          // 4 values/thread
            a += __hip_atomic_load(&partial[i * THREADS + t],
                                   __ATOMIC_RELAXED, __HIP_MEMORY_SCOPE_AGENT);
#pragma unroll
        for (int off = 32; off > 0; off >>= 1)
            a += __shfl_down(a, off, 64);
        if ((t & 63) == 0) wsum[t >> 6] = a;
        __syncthreads();
        if (t == 0)
            out[0] = (wsum[0] + wsum[1] + wsum[2] + wsum[3]) * (1.0f / (float)NB);
    }
}

extern "C" void kernel_launch(void* const* d_in, const int* in_sizes, int n_in,
                              void* d_out, int out_size, void* d_ws, size_t ws_size,
                              hipStream_t stream) {
    const char* pred = (const char*)d_in[0];   // [B, C, T] f32
    const char* lab  = (const char*)d_in[1];   // [B, T] int32
    float* out = (float*)d_out;                // scalar f32

    unsigned* counter = (unsigned*)d_ws;                    // 4 B, zeroed per call
    float*    partial = (float*)((char*)d_ws + 256);        // 1024 f32, fully rewritten

    hipMemsetAsync(d_ws, 0, 4, stream);        // capture-legal (memset node)
    ce_lsr_fused<<<NBLOCKS, THREADS, 0, stream>>>(pred, lab, partial, counter, out);
}

// Round 5
// 43.417 us; speedup vs baseline: 1.7139x; 1.7139x over previous
//
#include <hip/hip_runtime.h>
#include <stdint.h>

// loss = mean_b sum_t [ valid * ( lse(x) - (S/C)*sum_c x_c - (1-S)*x_label ) ]
// Memory-bound: 125.8 MB pred (f32) + 41.9 MB labels (i32) -> one f32 out.
// Fused single kernel, fence-free last-block-done reduce:
//   relaxed sc1 atomic store of partial -> s_waitcnt vmcnt(0) (completion ==
//   device visibility, NO buffer_wbl2/inv cache maintenance) -> relaxed
//   fetch_add on counter. LDS kept at exactly 40960 B -> 4 blocks/CU.

constexpr int   FILLUP  = -100;
constexpr float BASEP   = 0.2f / 3.0f;   // SMOOTHING / C
constexpr float CONF    = 0.8f;          // 1 - SMOOTHING
constexpr int   NB      = 2097152;       // B
constexpr int   THREADS = 256;
constexpr int   CROWS   = 256;                    // rows per chunk
constexpr int   NCHUNK  = NB / CROWS;             // 8192
constexpr int   CPB     = 8;                      // chunks per block
constexpr int   NBLOCKS = NCHUNK / CPB;           // 1024 = 4/CU x 256 CU
constexpr int   PRED_CB = CROWS * 15 * 4;         // 15360 B per chunk
constexpr int   LAB_CB  = CROWS * 5 * 4;          // 5120 B per chunk
constexpr int   PRED_SLOTS = PRED_CB / 16;        // 960 x 16B
constexpr int   LAB_SLOTS  = LAB_CB / 16;         // 320 x 16B

__device__ __forceinline__ void gll16(const void* g, void* l) {
    __builtin_amdgcn_global_load_lds(
        (const __attribute__((address_space(1))) void*)g,
        (__attribute__((address_space(3))) void*)l, 16, 0, 0);
}

__device__ __forceinline__ void stage_chunk(const char* __restrict__ predB,
                                            const char* __restrict__ labB,
                                            int chunk, char* predL, char* labL,
                                            int t) {
    const char* ps = predB + (size_t)chunk * PRED_CB;
    const char* ls = labB  + (size_t)chunk * LAB_CB;
#pragma unroll
    for (int i = 0; i < 4; ++i) {                 // 960 slots (wave-aligned tail)
        const int idx = i * THREADS + t;
        if (idx < PRED_SLOTS) gll16(ps + (size_t)idx * 16, predL + idx * 16);
    }
#pragma unroll
    for (int i = 0; i < 2; ++i) {                 // 320 slots
        const int idx = i * THREADS + t;
        if (idx < LAB_SLOTS) gll16(ls + (size_t)idx * 16, labL + idx * 16);
    }
}

__global__ __launch_bounds__(THREADS)
void ce_lsr_fused(const char* __restrict__ predB,
                  const char* __restrict__ labB,
                  float* __restrict__ partial,
                  unsigned* __restrict__ counter,
                  float* __restrict__ out) {
    // 2 x (15360 + 5120) = 40960 B EXACTLY -> 4 blocks/CU (16 waves)
    __shared__ __align__(16) char predS[2][PRED_CB];
    __shared__ __align__(16) char labS[2][LAB_CB];

    const int t = threadIdx.x;
    const int cbase = blockIdx.x * CPB;

    stage_chunk(predB, labB, cbase, predS[0], labS[0], t);   // cold start (once)
    __syncthreads();

    float acc = 0.0f;
    for (int k = 0; k < CPB; ++k) {
        const int cur = k & 1;
        if (k + 1 < CPB)                                     // prefetch BEFORE compute
            stage_chunk(predB, labB, cbase + k + 1, predS[cur ^ 1], labS[cur ^ 1], t);

        // 1 row/thread; LDS row stride 15 dwords (2-way aliasing = free, m136)
        const float* __restrict__ xr = (const float*)(predS[cur]) + t * 15;
        const int*   __restrict__ lr = (const int*)(labS[cur]) + t * 5;
#pragma unroll
        for (int tt = 0; tt < 5; ++tt) {
            const int   l  = lr[tt];
            const float x0 = xr[tt];
            const float x1 = xr[5 + tt];
            const float x2 = xr[10 + tt];
            const float m   = fmaxf(fmaxf(x0, x1), x2);
            const float s   = __expf(x0 - m) + __expf(x1 - m) + __expf(x2 - m);
            const float lse = m + __logf(s);
            const float xl  = (l == 1) ? x1 : ((l == 2) ? x2 : x0);
            const float c   = lse - BASEP * (x0 + x1 + x2) - CONF * xl;
            acc += (l != FILLUP) ? c : 0.0f;
        }
        __syncthreads();   // buf(k+1) ready + protects buf reuse
    }

    // block reduce: wave shuffle, then cross-wave via reused staging LDS
#pragma unroll
    for (int off = 32; off > 0; off >>= 1)
        acc += __shfl_down(acc, off, 64);

    float* wsum = (float*)predS;          // staging LDS free after loop-end barrier
    int*   flag = (int*)predS + 8;        // broadcast slot (no extra __shared__!)
    if ((t & 63) == 0) wsum[t >> 6] = acc;
    __syncthreads();

    if (t == 0) {
        const float s = wsum[0] + wsum[1] + wsum[2] + wsum[3];
        // relaxed agent-scope store: sc1 write-through to coherence point,
        // NO wbl2/inv cache maintenance
        __hip_atomic_store(&partial[blockIdx.x], s,
                           __ATOMIC_RELAXED, __HIP_MEMORY_SCOPE_AGENT);
        // completion == device-wide visibility; cheap manual "release"
        asm volatile("s_waitcnt vmcnt(0)" ::: "memory");
        const unsigned prev = __hip_atomic_fetch_add(counter, 1u,
                           __ATOMIC_RELAXED, __HIP_MEMORY_SCOPE_AGENT);
        *flag = (prev == NBLOCKS - 1) ? 1 : 0;
    }
    __syncthreads();
    const bool isLast = (*flag != 0);

    if (isLast) {
        // exactly one block; fixed reduction tree -> bitwise deterministic
        float a = 0.0f;
#pragma unroll
        for (int i = 0; i < NBLOCKS / THREADS; ++i)          // 4 sc1 loads/thread
            a += __hip_atomic_load(&partial[i * THREADS + t],
                                   __ATOMIC_RELAXED, __HIP_MEMORY_SCOPE_AGENT);
#pragma unroll
        for (int off = 32; off > 0; off >>= 1)
            a += __shfl_down(a, off, 64);
        __syncthreads();                  // wsum slots reused: all prior reads done
        if ((t & 63) == 0) wsum[t >> 6] = a;
        __syncthreads();
        if (t == 0)
            out[0] = (wsum[0] + wsum[1] + wsum[2] + wsum[3]) * (1.0f / (float)NB);
    }
}

extern "C" void kernel_launch(void* const* d_in, const int* in_sizes, int n_in,
                              void* d_out, int out_size, void* d_ws, size_t ws_size,
                              hipStream_t stream) {
    const char* pred = (const char*)d_in[0];   // [B, C, T] f32
    const char* lab  = (const char*)d_in[1];   // [B, T] int32
    float* out = (float*)d_out;                // scalar f32

    unsigned* counter = (unsigned*)d_ws;                 // 4 B, zeroed per call
    float*    partial = (float*)((char*)d_ws + 256);     // 1024 f32, rewritten per call

    hipMemsetAsync(d_ws, 0, 4, stream);        // capture-legal memset node
    ce_lsr_fused<<<NBLOCKS, THREADS, 0, stream>>>(pred, lab, partial, counter, out);
}

// Round 7
// 31.690 us; speedup vs baseline: 2.3482x; 1.3701x over previous
//
#include <hip/hip_runtime.h>
#include <stdint.h>

// loss = mean_b sum_t [ valid * ( lse(x) - (S/C)*sum_c x_c - (1-S)*x_label ) ]
// Memory-bound: 125.8 MB pred (f32) + 41.9 MB labels (i32) -> one f32 out.
// T3/T4 counted-vmcnt streaming: raw s_barrier + s_waitcnt vmcnt(5) keeps the
// next chunk's loads in flight across the barrier (no vmcnt(0) drain bubble).
// Unified slot space (pred||lab contiguous per buffer) -> every wave issues
// exactly 5 global_load_lds per chunk -> uniform static vmcnt immediate.

constexpr int   FILLUP  = -100;
constexpr float BASEP   = 0.2f / 3.0f;   // SMOOTHING / C
constexpr float CONF    = 0.8f;          // 1 - SMOOTHING
constexpr int   NB      = 2097152;       // B
constexpr int   THREADS = 256;
constexpr int   CROWS   = 256;                    // rows per chunk
constexpr int   CPB     = 8;                      // chunks per block
constexpr int   NBLOCKS = NB / (CROWS * CPB);     // 1024 = 4/CU x 256 CU
constexpr int   PRED_CB = CROWS * 15 * 4;         // 15360 B per chunk
constexpr int   LAB_CB  = CROWS * 5 * 4;          // 5120 B per chunk
constexpr int   BUF_B   = PRED_CB + LAB_CB;       // 20480 B per buffer
constexpr int   SLOTS   = BUF_B / 16;             // 1280 = 5 * 256 exactly
constexpr int   PRED_SLOTS = PRED_CB / 16;        // 960 (= wave-aligned boundary)

__device__ __forceinline__ void gll16(const void* g, void* l) {
    // async global->LDS, 16B/lane; LDS dest pattern = uniform base + lane*16
    __builtin_amdgcn_global_load_lds(
        (const __attribute__((address_space(1))) void*)g,
        (__attribute__((address_space(3))) void*)l, 16, 0, 0);
}

// Issue exactly 5 gll16 per wave: slot < 960 -> pred, else lab.
// Global src is per-lane (fine); LDS dest = buf + slot*16 (linear, uniform+lane*16).
__device__ __forceinline__ void stage_chunk(const char* __restrict__ predB,
                                            const char* __restrict__ labB,
                                            int chunk, char* buf, int t) {
    const char* ps = predB + (size_t)chunk * PRED_CB;
    const char* ls = labB  + (size_t)chunk * LAB_CB;
#pragma unroll
    for (int i = 0; i < 5; ++i) {
        const int slot = i * THREADS + t;         // 0..1279, no masking
        const char* src = (slot < PRED_SLOTS)
                        ? ps + (size_t)slot * 16
                        : ls + (size_t)(slot - PRED_SLOTS) * 16;
        gll16(src, buf + slot * 16);
    }
}

__global__ __launch_bounds__(THREADS)
void ce_lsr_stage1(const char* __restrict__ predB,
                   const char* __restrict__ labB,
                   float* __restrict__ partial) {
    // 2 x 20480 = 40960 B EXACTLY -> 4 blocks/CU (16 waves)
    __shared__ __align__(16) char bufS[2][BUF_B];

    const int t = threadIdx.x;
    const int cbase = blockIdx.x * CPB;

    stage_chunk(predB, labB, cbase, bufS[0], t);      // 5 loads/wave in flight

    float acc = 0.0f;
#pragma unroll
    for (int k = 0; k < CPB; ++k) {
        const int cur = k & 1;
        if (k + 1 < CPB) {
            stage_chunk(predB, labB, cbase + k + 1, bufS[cur ^ 1], t); // +5
            // wait chunk k's 5 oldest loads; k+1's 5 stay IN FLIGHT
            asm volatile("s_waitcnt vmcnt(5)" ::: "memory");
        } else {
            asm volatile("s_waitcnt vmcnt(0)" ::: "memory");           // tail drain
        }
        __builtin_amdgcn_sched_barrier(0);
        __builtin_amdgcn_s_barrier();      // B: all waves have chunk k (no auto-drain)

        // 1 row/thread; LDS row stride 15 dwords (2-way aliasing = free, m136)
        const float* __restrict__ xr = (const float*)(bufS[cur]) + t * 15;
        const int*   __restrict__ lr = (const int*)(bufS[cur] + PRED_CB) + t * 5;
#pragma unroll
        for (int tt = 0; tt < 5; ++tt) {
            const int   l  = lr[tt];
            const float x0 = xr[tt];
            const float x1 = xr[5 + tt];
            const float x2 = xr[10 + tt];
            const float m   = fmaxf(fmaxf(x0, x1), x2);
            const float s   = __expf(x0 - m) + __expf(x1 - m) + __expf(x2 - m);
            const float lse = m + __logf(s);
            const float xl  = (l == 1) ? x1 : ((l == 2) ? x2 : x0);
            const float c   = lse - BASEP * (x0 + x1 + x2) - CONF * xl;
            acc += (l != FILLUP) ? c : 0.0f;
        }
        __builtin_amdgcn_s_barrier();      // A: chunk-k readers done -> buf reusable
    }

    // block reduce: wave shuffle, then cross-wave via reused staging LDS
#pragma unroll
    for (int off = 32; off > 0; off >>= 1)
        acc += __shfl_down(acc, off, 64);

    float* wsum = (float*)bufS;            // LDS free: all loads drained (vmcnt(0))
    if ((t & 63) == 0) wsum[t >> 6] = acc;
    __syncthreads();
    if (t == 0)
        partial[blockIdx.x] = wsum[0] + wsum[1] + wsum[2] + wsum[3];
}

__global__ __launch_bounds__(256)
void ce_lsr_stage2(const float* __restrict__ partial,
                   float* __restrict__ out) {
    float acc = 0.0f;
#pragma unroll
    for (int i = 0; i < NBLOCKS / 256; ++i)          // 4 values/thread
        acc += partial[i * 256 + threadIdx.x];
#pragma unroll
    for (int off = 32; off > 0; off >>= 1)
        acc += __shfl_down(acc, off, 64);

    __shared__ float wsum[4];
    const int lane = threadIdx.x & 63;
    const int wid  = threadIdx.x >> 6;
    if (lane == 0) wsum[wid] = acc;
    __syncthreads();
    if (threadIdx.x == 0) {
        const float s = wsum[0] + wsum[1] + wsum[2] + wsum[3];
        out[0] = s * (1.0f / (float)NB);
    }
}

extern "C" void kernel_launch(void* const* d_in, const int* in_sizes, int n_in,
                              void* d_out, int out_size, void* d_ws, size_t ws_size,
                              hipStream_t stream) {
    const char* pred = (const char*)d_in[0];   // [B, C, T] f32
    const char* lab  = (const char*)d_in[1];   // [B, T] int32
    float* out     = (float*)d_out;            // scalar f32
    float* partial = (float*)d_ws;             // 1024 f32, fully rewritten per call

    ce_lsr_stage1<<<NBLOCKS, THREADS, 0, stream>>>(pred, lab, partial);
    ce_lsr_stage2<<<1, 256, 0, stream>>>(partial, out);
}